// Round 3
// baseline (8727.391 us; speedup 1.0000x reference)
//
#include <hip/hip_runtime.h>
#include <cstdint>

// VAN checkerboard sampler, LEVEL=0, B=4096, L=16, H=32, K=5.
// Maintained-a2 incremental design with ~50% block-uniform skip.
// R3: LDS cut 134KB -> ~69KB and VGPR pinned <=64 so 2 blocks/CU are resident
// (round-2's 1-block residency exposed every barrier drain -> 61% VALUBusy).
// Kahan dropped (drift ~1e-7 in logit, flip risk <1%); staging 8 buffers;
// init uses a rolling 5-row h1 window inside the staging buffer.

struct U2 { uint32_t x, y; };

// JAX Threefry-2x32 (20 rounds) — verified bit-exact in rounds 1-2
__device__ __forceinline__ U2 tf2x32(uint32_t k0, uint32_t k1, uint32_t x0, uint32_t x1) {
  uint32_t k2 = k0 ^ k1 ^ 0x1BD11BDAu;
#define TFROT(r) { x0 += x1; x1 = (x1 << (r)) | (x1 >> (32 - (r))); x1 ^= x0; }
  x0 += k0; x1 += k1;
  TFROT(13) TFROT(15) TFROT(26) TFROT(6)
  x0 += k1; x1 += k2 + 1u;
  TFROT(17) TFROT(29) TFROT(16) TFROT(24)
  x0 += k2; x1 += k0 + 2u;
  TFROT(13) TFROT(15) TFROT(26) TFROT(6)
  x0 += k0; x1 += k1 + 3u;
  TFROT(17) TFROT(29) TFROT(16) TFROT(24)
  x0 += k1; x1 += k2 + 4u;
  TFROT(13) TFROT(15) TFROT(26) TFROT(6)
  x0 += k2; x1 += k0 + 5u;
#undef TFROT
  return {x0, x1};
}

__device__ __forceinline__ float lrelu(float v) { return fmaxf(v, 0.1f * v); }

#define HOFF 4096   // rolling h1 window lives at s_buf[HOFF .. HOFF+2560)

__launch_bounds__(1024, 8)
__global__ void van_kernel(const float* __restrict__ gx,
                           const float* __restrict__ gw1, const float* __restrict__ gb1,
                           const float* __restrict__ gw2, const float* __restrict__ gb2,
                           const float* __restrict__ gw3, const float* __restrict__ gb3,
                           float* __restrict__ out, int B) {
  __shared__ __align__(16) float s_xf[784];        // x with +/-6 circular halo (28x28)
  __shared__ __align__(16) float s_w1[800];
  __shared__ float s_b1[32], s_b2[32];
  __shared__ float s_u[64];
  __shared__ float s_c3[16];
  __shared__ __align__(16) float s_h1d[800];       // delta_h1: [pos25][ic32]
  __shared__ __align__(16) float s_a2[8192];       // a2 (+b2): [(row*16+col)*32+oc]
  __shared__ __align__(16) float s_buf[6912];      // staging 8x864 (main) / 8x512 + h1-roll (init)

  const int tid  = threadIdx.x;
  const int bg   = blockIdx.x;
  const int lane = tid & 63;
  const int wv   = tid >> 6;
  const int oc   = tid & 31;   // conv2 out-channel
  const int ic   = tid >> 5;   // conv2 in-channel

  // ---------------- setup ----------------
  const float b3v = gb3[0];
  float w2r[25];
  {
    const float* p = gw2 + (oc * 32 + ic) * 25;    // w2[oc][ic][ky][kx]
    #pragma unroll
    for (int k = 0; k < 25; ++k) w2r[k] = p[k];
  }
  float w3r = 0.f;
  if (tid < 800) w3r = gw3[(tid & 31) * 25 + (tid >> 5)];   // w3[oc][pos], thread-fixed
  if (tid < 800) s_w1[tid] = gw1[tid];
  if (tid < 32)  { s_b1[tid] = gb1[tid]; s_b2[tid] = gb2[tid]; }
  if (tid < 784) {
    int rr = tid / 28, cc = tid - rr * 28;
    s_xf[tid] = gx[bg * 256 + ((rr - 6) & 15) * 16 + ((cc - 6) & 15)];
  }
  if (tid < 64) {
    U2 key = tf2x32(0u, 42u, 0u, (uint32_t)tid);
    U2 tt  = tf2x32(key.x, key.y, 0u, (uint32_t)bg);
    uint32_t bits = tt.x ^ tt.y;
    s_u[tid] = __uint_as_float(0x3F800000u | (bits >> 9)) - 1.0f;
  }
  __syncthreads();

  // ---------------- init: rolling h1 (5 rows) + a2 field ----------------
  // gen g holds field row (14+g)&15 at roll slot g%5.
  if (tid < 512) {
    const int colG = tid >> 5, icG = tid & 31;
    #pragma unroll 1
    for (int g = 0; g < 5; ++g) {
      int f = (14 + g) & 15;
      float a = s_b1[icG];
      #pragma unroll
      for (int ky = 0; ky < 5; ++ky)
        #pragma unroll
        for (int kx = 0; kx < 5; ++kx)
          a = fmaf(s_xf[(f + 4 + ky) * 28 + colG + 4 + kx], s_w1[icG * 25 + ky * 5 + kx], a);
      s_buf[HOFF + g * 512 + tid] = lrelu(a);
    }
  }
  __syncthreads();

  #pragma unroll 1
  for (int t = 0; t < 16; ++t) {          // a2 output row t
    float acc[16];
    #pragma unroll
    for (int X = 0; X < 16; ++X) acc[X] = 0.f;
    #pragma unroll
    for (int ky = 0; ky < 5; ++ky) {
      int slot = (t + ky) % 5;            // gen t+ky = field row (t+ky-2)&15
      float h[16];
      #pragma unroll
      for (int col = 0; col < 16; ++col) h[col] = s_buf[HOFF + slot * 512 + col * 32 + ic];
      #pragma unroll
      for (int kx = 0; kx < 5; ++kx) {
        float w = w2r[ky * 5 + kx];
        #pragma unroll
        for (int X = 0; X < 16; ++X)
          acc[X] = fmaf(h[(X + kx - 2) & 15], w, acc[X]);
      }
    }
    #pragma unroll
    for (int X = 0; X < 16; ++X) acc[X] += __shfl_xor(acc[X], 32, 64);
    if (wv >= 8 && lane < 32) {
      #pragma unroll
      for (int X = 0; X < 16; ++X) s_buf[(wv - 8) * 512 + X * 32 + lane] = acc[X];
    }
    __syncthreads();
    if (wv < 8 && lane < 32) {
      #pragma unroll
      for (int X = 0; X < 16; ++X) s_buf[wv * 512 + X * 32 + lane] += acc[X];
    }
    __syncthreads();
    if (tid < 512) {
      float sm = 0.f;
      #pragma unroll
      for (int v = 0; v < 8; ++v) sm += s_buf[v * 512 + tid];
      s_a2[t * 512 + tid] = sm + s_b2[tid & 31];
    } else {
      // generate gen t+5 into slot (t+5)%5 == t%5 (its old reads finished pre-B1)
      int t2 = tid - 512;
      int colG = t2 >> 5, icG = t2 & 31;
      int f = (14 + t + 5) & 15;
      float a = s_b1[icG];
      #pragma unroll
      for (int ky = 0; ky < 5; ++ky)
        #pragma unroll
        for (int kx = 0; kx < 5; ++kx)
          a = fmaf(s_xf[(f + 4 + ky) * 28 + colG + 4 + kx], s_w1[icG * 25 + ky * 5 + kx], a);
      s_buf[HOFF + (t % 5) * 512 + t2] = lrelu(a);
    }
    __syncthreads();
  }

  // ---------------- main autoregressive loop ----------------
  float logq = 0.f;
  #pragma unroll 1
  for (int s = 0; s < 64; ++s) {
    const int i = 2 * (s >> 3) + 1;
    const int j = 2 * (s & 7) + 1;

    // ---- conv3 from maintained a2 ----
    float v3 = 0.f;
    if (tid < 800) {
      int p = tid >> 5, o2 = tid & 31;
      int dy = p / 5, dx = p - 5 * dy;
      int idx = (((i + dy - 2) & 15) * 16 + ((j + dx - 2) & 15)) * 32 + o2;
      v3 = lrelu(s_a2[idx]) * w3r;
    }
    #pragma unroll
    for (int m = 32; m >= 1; m >>= 1) v3 += __shfl_xor(v3, m, 64);
    if (lane == 0) s_c3[wv] = v3;
    __syncthreads();

    // ---- sample (all threads, redundant & identical) ----
    float logit = b3v;
    #pragma unroll
    for (int v = 0; v < 16; ++v) logit += s_c3[v];
    const float pr   = 1.f / (1.f + expf(-logit));
    const float u    = s_u[s];
    const float samp = (u < pr) ? 1.f : -1.f;
    const float xold = s_xf[(i + 6) * 28 + (j + 6)];
    logq += (samp > 0.f) ? logf(pr + 1e-7f) : logf(1.f - pr + 1e-7f);

    if (samp == xold) { __syncthreads(); continue; }   // block-uniform skip (~50%)

    // ---- phase A: delta_h1 at 25 positions x 32 ic ----
    if (tid < 800) {
      int p = tid >> 5, icA = tid & 31;
      int dyq = p / 5, dxq = p - 5 * dyq;
      const float* wp = &s_w1[icA * 25];
      float a1v = s_b1[icA];
      int base = (i + dyq + 2) * 28 + (j + dxq + 2);
      #pragma unroll
      for (int ky = 0; ky < 5; ++ky)
        #pragma unroll
        for (int kx = 0; kx < 5; ++kx)
          a1v = fmaf(s_xf[base + ky * 28 + kx], wp[ky * 5 + kx], a1v);
      float delta = samp - xold;                       // +/-2
      float a1n = fmaf(delta, wp[(4 - dyq) * 5 + (4 - dxq)], a1v);
      s_h1d[p * 32 + icA] = lrelu(a1n) - lrelu(a1v);
    }
    __syncthreads();

    if (tid == 1023) {                                 // update x halo copies
      int r1 = i + 6, c1 = j + 6;
      int r2 = (i < 6) ? i + 22 : ((i >= 10) ? i - 10 : r1);
      int c2 = (j < 6) ? j + 22 : ((j >= 10) ? j - 10 : c1);
      s_xf[r1 * 28 + c1] = samp; s_xf[r1 * 28 + c2] = samp;
      s_xf[r2 * 28 + c1] = samp; s_xf[r2 * 28 + c2] = samp;
    }

    // ---- phase B: 5x5 delta_h1 (*) w2 -> 9x9 a2 update, 3 chunks of 3 rows ----
    #pragma unroll
    for (int cch = 0; cch < 3; ++cch) {
      float acc[27];
      #pragma unroll
      for (int q = 0; q < 27; ++q) acc[q] = 0.f;
      #pragma unroll
      for (int dyp = 0; dyp < 5; ++dyp) {
        if (dyp + 4 < 3 * cch || dyp + 4 > 3 * cch + 6) continue;   // folds at compile time
        float h[5];
        #pragma unroll
        for (int dxp = 0; dxp < 5; ++dxp) h[dxp] = s_h1d[(dyp * 5 + dxp) * 32 + ic];
        #pragma unroll
        for (int u2 = 0; u2 < 3; ++u2) {
          const int ky = dyp + 4 - 3 * cch - u2;
          if (ky < 0 || ky > 4) continue;              // folds at compile time
          #pragma unroll
          for (int kx = 0; kx < 5; ++kx) {
            const float w = w2r[ky * 5 + kx];
            #pragma unroll
            for (int dxp = 0; dxp < 5; ++dxp)
              acc[u2 * 9 + dxp - kx + 4] = fmaf(h[dxp], w, acc[u2 * 9 + dxp - kx + 4]);
          }
        }
      }
      #pragma unroll
      for (int q = 0; q < 27; ++q) acc[q] += __shfl_xor(acc[q], 32, 64);
      if (wv >= 8 && lane < 32) {
        #pragma unroll
        for (int q = 0; q < 27; ++q) s_buf[(wv - 8) * 864 + q * 32 + lane] = acc[q];
      }
      __syncthreads();
      if (wv < 8 && lane < 32) {
        #pragma unroll
        for (int q = 0; q < 27; ++q) s_buf[wv * 864 + q * 32 + lane] += acc[q];
      }
      __syncthreads();
      if (tid < 864) {
        float sm = 0.f;
        #pragma unroll
        for (int v = 0; v < 8; ++v) sm += s_buf[v * 864 + tid];
        int u3 = tid / 288, rem = tid - u3 * 288;
        int V = rem >> 5, o3 = rem & 31;
        int idx = (((i - 4 + 3 * cch + u3) & 15) * 16 + ((j - 4 + V) & 15)) * 32 + o3;
        s_a2[idx] += sm;
      }
      __syncthreads();
    }
  }

  // ---------------- output ----------------
  if (tid < 256)
    out[bg * 256 + tid] = s_xf[((tid >> 4) + 6) * 28 + (tid & 15) + 6];
  if (tid == 0)
    out[B * 256 + bg] = logq;
}

extern "C" void kernel_launch(void* const* d_in, const int* in_sizes, int n_in,
                              void* d_out, int out_size, void* d_ws, size_t ws_size,
                              hipStream_t stream) {
  const float* gx  = (const float*)d_in[0];
  const float* gw1 = (const float*)d_in[1];
  const float* gb1 = (const float*)d_in[2];
  const float* gw2 = (const float*)d_in[3];
  const float* gb2 = (const float*)d_in[4];
  const float* gw3 = (const float*)d_in[5];
  const float* gb3 = (const float*)d_in[6];
  float* out = (float*)d_out;
  const int B = in_sizes[0] / 256;

  hipLaunchKernelGGL(van_kernel, dim3(B), dim3(1024), 0, stream,
                     gx, gw1, gb1, gw2, gb2, gw3, gb3, out, B);
}

// Round 4
// 8711.295 us; speedup vs baseline: 1.0018x; 1.0018x over previous
//
#include <hip/hip_runtime.h>
#include <cstdint>

// VAN checkerboard sampler, LEVEL=0, B=4096, L=16, H=32, K=5.
// Maintained-a2 incremental design with ~50% block-uniform skip.
// R4: 512-thread blocks + __launch_bounds__(512,4) -> 128-VGPR cap, 2 blocks/CU
// by LDS (~69KB) and VGPR alike. R3's (1024,8) forced a 64-reg cap onto a ~95-reg
// working set -> scratch spill storm (13.7 GB HBM traffic). Each thread now owns
// TWO w2 slices (ic, ic+16); phase B stages via a single 8-way buffer write
// (8 barriers/update-step, was 11). Init recomputes a 5-row h1 window per a2 row
// (aliased into staging) - ~2K extra FMA total, no extra LDS.

struct U2 { uint32_t x, y; };

// JAX Threefry-2x32 (20 rounds) — verified bit-exact in rounds 1-3
__device__ __forceinline__ U2 tf2x32(uint32_t k0, uint32_t k1, uint32_t x0, uint32_t x1) {
  uint32_t k2 = k0 ^ k1 ^ 0x1BD11BDAu;
#define TFROT(r) { x0 += x1; x1 = (x1 << (r)) | (x1 >> (32 - (r))); x1 ^= x0; }
  x0 += k0; x1 += k1;
  TFROT(13) TFROT(15) TFROT(26) TFROT(6)
  x0 += k1; x1 += k2 + 1u;
  TFROT(17) TFROT(29) TFROT(16) TFROT(24)
  x0 += k2; x1 += k0 + 2u;
  TFROT(13) TFROT(15) TFROT(26) TFROT(6)
  x0 += k0; x1 += k1 + 3u;
  TFROT(17) TFROT(29) TFROT(16) TFROT(24)
  x0 += k1; x1 += k2 + 4u;
  TFROT(13) TFROT(15) TFROT(26) TFROT(6)
  x0 += k2; x1 += k0 + 5u;
#undef TFROT
  return {x0, x1};
}

__device__ __forceinline__ float lrelu(float v) { return fmaxf(v, 0.1f * v); }

#define WOFF 4096   // init h1 window lives at s_stage[WOFF .. WOFF+2560)

// phase-B partial: 5x5 delta_h1(ic) (*) w2 -> 3 output rows (chunk CCH), acc[27]
template<int CCH>
__device__ __forceinline__ void pb_accum(const float (&w2)[25], const float* h1d_ic,
                                         float (&acc)[27]) {
  #pragma unroll
  for (int dyp = 0; dyp < 5; ++dyp) {
    if (dyp + 4 < 3 * CCH || dyp + 4 > 3 * CCH + 6) continue;   // compile-time fold
    float h[5];
    #pragma unroll
    for (int dxp = 0; dxp < 5; ++dxp) h[dxp] = h1d_ic[(dyp * 5 + dxp) * 32];
    #pragma unroll
    for (int u2 = 0; u2 < 3; ++u2) {
      const int ky = dyp + 4 - 3 * CCH - u2;
      if (ky < 0 || ky > 4) continue;                           // compile-time fold
      #pragma unroll
      for (int kx = 0; kx < 5; ++kx) {
        const float w = w2[ky * 5 + kx];
        #pragma unroll
        for (int dxp = 0; dxp < 5; ++dxp)
          acc[u2 * 9 + dxp - kx + 4] = fmaf(h[dxp], w, acc[u2 * 9 + dxp - kx + 4]);
      }
    }
  }
}

template<int CCH>
__device__ __forceinline__ void pb_chunk(const float (&w2a)[25], const float (&w2b)[25],
                                         int icp, const float* s_h1d, float* s_stage,
                                         float* s_a2, int tid, int lane, int wv,
                                         int i, int j) {
  float acc[27];
  #pragma unroll
  for (int q = 0; q < 27; ++q) acc[q] = 0.f;
  pb_accum<CCH>(w2a, s_h1d + icp, acc);
  pb_accum<CCH>(w2b, s_h1d + icp + 16, acc);
  #pragma unroll
  for (int q = 0; q < 27; ++q) acc[q] += __shfl_xor(acc[q], 32, 64);
  if (lane < 32) {
    #pragma unroll
    for (int q = 0; q < 27; ++q) s_stage[wv * 864 + q * 32 + lane] = acc[q];
  }
  __syncthreads();
  for (int e = tid; e < 864; e += 512) {
    float sm = 0.f;
    #pragma unroll
    for (int w = 0; w < 8; ++w) sm += s_stage[w * 864 + e];
    int q = e >> 5, o3 = e & 31;
    int u2 = q / 9, V = q - 9 * u2;
    int idx = (((i - 4 + 3 * CCH + u2) & 15) * 16 + ((j - 4 + V) & 15)) * 32 + o3;
    s_a2[idx] += sm;
  }
  __syncthreads();
}

// init conv2 partial for one a2 row, one ic: 16 columns
__device__ __forceinline__ void init_conv2_half(const float (&w2)[25], int icc,
                                                const float* s_stage, float (&acc)[16]) {
  #pragma unroll
  for (int ky = 0; ky < 5; ++ky) {
    float h[16];
    #pragma unroll
    for (int col = 0; col < 16; ++col) h[col] = s_stage[WOFF + ky * 512 + col * 32 + icc];
    #pragma unroll
    for (int kx = 0; kx < 5; ++kx) {
      const float w = w2[ky * 5 + kx];
      #pragma unroll
      for (int X = 0; X < 16; ++X)
        acc[X] = fmaf(h[(X + kx - 2) & 15], w, acc[X]);
    }
  }
}

__launch_bounds__(512, 4)
__global__ void van_kernel(const float* __restrict__ gx,
                           const float* __restrict__ gw1, const float* __restrict__ gb1,
                           const float* __restrict__ gw2, const float* __restrict__ gb2,
                           const float* __restrict__ gw3, const float* __restrict__ gb3,
                           float* __restrict__ out, int B) {
  __shared__ __align__(16) float s_xf[784];        // x with +/-6 circular halo (28x28)
  __shared__ __align__(16) float s_w1[800];
  __shared__ float s_b1[32], s_b2[32];
  __shared__ float s_u[64];
  __shared__ float s_c3[8];
  __shared__ __align__(16) float s_h1d[800];       // delta_h1: [pos25][ic32]
  __shared__ __align__(16) float s_a2[8192];       // a2 (+b2): [(row*16+col)*32+oc]
  __shared__ __align__(16) float s_stage[6912];    // 8x864 (main) / 8x512 + h1 window (init)

  const int tid  = threadIdx.x;
  const int bg   = blockIdx.x;
  const int lane = tid & 63;
  const int wv   = tid >> 6;
  const int oc   = tid & 31;   // conv2 out-channel
  const int icp  = tid >> 5;   // conv2 in-channel pair base: handles icp and icp+16

  // ---------------- setup ----------------
  const float b3v = gb3[0];
  float w2a[25], w2b[25];
  {
    const float* pa = gw2 + (oc * 32 + icp) * 25;         // w2[oc][icp][.]
    const float* pb = gw2 + (oc * 32 + icp + 16) * 25;    // w2[oc][icp+16][.]
    #pragma unroll
    for (int k = 0; k < 25; ++k) { w2a[k] = pa[k]; w2b[k] = pb[k]; }
  }
  float w3r1 = gw3[(tid & 31) * 25 + (tid >> 5)];         // entry e=tid: w3[oc][p]
  float w3r2 = 0.f;
  if (tid < 288) {
    int e = tid + 512;
    w3r2 = gw3[(e & 31) * 25 + (e >> 5)];
  }
  s_w1[tid] = gw1[tid];
  if (tid < 288) s_w1[tid + 512] = gw1[tid + 512];
  if (tid < 32)  { s_b1[tid] = gb1[tid]; s_b2[tid] = gb2[tid]; }
  {
    int rr = tid / 28, cc = tid - rr * 28;
    s_xf[tid] = gx[bg * 256 + ((rr - 6) & 15) * 16 + ((cc - 6) & 15)];
    if (tid < 272) {
      int t2 = tid + 512;
      int r2 = t2 / 28, c2 = t2 - r2 * 28;
      s_xf[t2] = gx[bg * 256 + ((r2 - 6) & 15) * 16 + ((c2 - 6) & 15)];
    }
  }
  if (tid < 64) {
    U2 key = tf2x32(0u, 42u, 0u, (uint32_t)tid);
    U2 tt  = tf2x32(key.x, key.y, 0u, (uint32_t)bg);
    uint32_t bits = tt.x ^ tt.y;
    s_u[tid] = __uint_as_float(0x3F800000u | (bits >> 9)) - 1.0f;
  }
  __syncthreads();

  // ---------------- init: a2 field row by row (h1 window recomputed) ----------------
  #pragma unroll 1
  for (int t = 0; t < 16; ++t) {
    // 5-row h1 window: slot r5 holds field row (t+r5-2)&15; thread = (col,ic)
    {
      const int colW = tid >> 5, icW = tid & 31;
      const float* wp = &s_w1[icW * 25];
      const float bb = s_b1[icW];
      #pragma unroll
      for (int r5 = 0; r5 < 5; ++r5) {
        int f = (t + r5 - 2) & 15;
        float a = bb;
        #pragma unroll
        for (int ky = 0; ky < 5; ++ky)
          #pragma unroll
          for (int kx = 0; kx < 5; ++kx)
            a = fmaf(s_xf[(f + 4 + ky) * 28 + colW + 4 + kx], wp[ky * 5 + kx], a);
        s_stage[WOFF + r5 * 512 + tid] = lrelu(a);
      }
    }
    __syncthreads();
    float acc[16];
    #pragma unroll
    for (int X = 0; X < 16; ++X) acc[X] = 0.f;
    init_conv2_half(w2a, icp, s_stage, acc);
    init_conv2_half(w2b, icp + 16, s_stage, acc);
    #pragma unroll
    for (int X = 0; X < 16; ++X) acc[X] += __shfl_xor(acc[X], 32, 64);
    if (lane < 32) {
      #pragma unroll
      for (int X = 0; X < 16; ++X) s_stage[wv * 512 + X * 32 + lane] = acc[X];
    }
    __syncthreads();
    {
      float sm = 0.f;
      #pragma unroll
      for (int w = 0; w < 8; ++w) sm += s_stage[w * 512 + tid];
      s_a2[t * 512 + tid] = sm + s_b2[tid & 31];
    }
    __syncthreads();
  }

  // ---------------- main autoregressive loop ----------------
  float logq = 0.f;
  #pragma unroll 1
  for (int s = 0; s < 64; ++s) {
    const int i = 2 * (s >> 3) + 1;
    const int j = 2 * (s & 7) + 1;

    // ---- conv3 from maintained a2 (800 terms over 512 threads) ----
    float v3;
    {
      int p1 = tid >> 5, o1 = tid & 31;
      int dy = p1 / 5, dx = p1 - 5 * dy;
      int idx = (((i + dy - 2) & 15) * 16 + ((j + dx - 2) & 15)) * 32 + o1;
      v3 = lrelu(s_a2[idx]) * w3r1;
      if (tid < 288) {
        int e = tid + 512, p2 = e >> 5, o2 = e & 31;
        int dy2 = p2 / 5, dx2 = p2 - 5 * dy2;
        int idx2 = (((i + dy2 - 2) & 15) * 16 + ((j + dx2 - 2) & 15)) * 32 + o2;
        v3 = fmaf(lrelu(s_a2[idx2]), w3r2, v3);
      }
    }
    #pragma unroll
    for (int m = 32; m >= 1; m >>= 1) v3 += __shfl_xor(v3, m, 64);
    if (lane == 0) s_c3[wv] = v3;
    __syncthreads();

    // ---- sample (all threads, redundant & identical) ----
    float logit = b3v;
    #pragma unroll
    for (int v = 0; v < 8; ++v) logit += s_c3[v];
    const float pr   = 1.f / (1.f + expf(-logit));
    const float u    = s_u[s];
    const float samp = (u < pr) ? 1.f : -1.f;
    const float xold = s_xf[(i + 6) * 28 + (j + 6)];
    logq += (samp > 0.f) ? logf(pr + 1e-7f) : logf(1.f - pr + 1e-7f);

    if (samp == xold) { __syncthreads(); continue; }   // block-uniform skip (~50%)

    // ---- phase A: delta_h1 at 25 positions x 32 ic (800 entries) ----
    {
      const float delta = samp - xold;                 // +/-2
      #pragma unroll
      for (int rep = 0; rep < 2; ++rep) {
        int e = tid + rep * 512;
        if (rep == 1 && tid >= 288) break;
        int p = e >> 5, icA = e & 31;
        int dyq = p / 5, dxq = p - 5 * dyq;
        const float* wp = &s_w1[icA * 25];
        float a1v = s_b1[icA];
        int base = (i + dyq + 2) * 28 + (j + dxq + 2);
        #pragma unroll
        for (int ky = 0; ky < 5; ++ky)
          #pragma unroll
          for (int kx = 0; kx < 5; ++kx)
            a1v = fmaf(s_xf[base + ky * 28 + kx], wp[ky * 5 + kx], a1v);
        float a1n = fmaf(delta, wp[(4 - dyq) * 5 + (4 - dxq)], a1v);
        s_h1d[p * 32 + icA] = lrelu(a1n) - lrelu(a1v);
      }
    }
    __syncthreads();

    if (tid == 511) {                                  // update x halo copies
      int r1 = i + 6, c1 = j + 6;
      int r2 = (i < 6) ? i + 22 : ((i >= 10) ? i - 10 : r1);
      int c2 = (j < 6) ? j + 22 : ((j >= 10) ? j - 10 : c1);
      s_xf[r1 * 28 + c1] = samp; s_xf[r1 * 28 + c2] = samp;
      s_xf[r2 * 28 + c1] = samp; s_xf[r2 * 28 + c2] = samp;
    }

    // ---- phase B: 5x5 delta_h1 (*) w2 -> 9x9 a2 update, 3 chunks x 3 rows ----
    pb_chunk<0>(w2a, w2b, icp, s_h1d, s_stage, s_a2, tid, lane, wv, i, j);
    pb_chunk<1>(w2a, w2b, icp, s_h1d, s_stage, s_a2, tid, lane, wv, i, j);
    pb_chunk<2>(w2a, w2b, icp, s_h1d, s_stage, s_a2, tid, lane, wv, i, j);
  }

  // ---------------- output ----------------
  if (tid < 256)
    out[bg * 256 + tid] = s_xf[((tid >> 4) + 6) * 28 + (tid & 15) + 6];
  if (tid == 0)
    out[B * 256 + bg] = logq;
}

extern "C" void kernel_launch(void* const* d_in, const int* in_sizes, int n_in,
                              void* d_out, int out_size, void* d_ws, size_t ws_size,
                              hipStream_t stream) {
  const float* gx  = (const float*)d_in[0];
  const float* gw1 = (const float*)d_in[1];
  const float* gb1 = (const float*)d_in[2];
  const float* gw2 = (const float*)d_in[3];
  const float* gb2 = (const float*)d_in[4];
  const float* gw3 = (const float*)d_in[5];
  const float* gb3 = (const float*)d_in[6];
  float* out = (float*)d_out;
  const int B = in_sizes[0] / 256;

  hipLaunchKernelGGL(van_kernel, dim3(B), dim3(512), 0, stream,
                     gx, gw1, gb1, gw2, gb2, gw3, gb3, out, B);
}

// Round 5
// 6053.042 us; speedup vs baseline: 1.4418x; 1.4392x over previous
//
#include <hip/hip_runtime.h>
#include <cstdint>

// VAN checkerboard sampler, LEVEL=0, B=4096, L=16, H=32, K=5.
// Maintained-a2 incremental design with ~50% block-uniform skip.
// R5: __launch_bounds__(512, 2). R3 (1024,8) and R4 (512,4) both produced a
// 64-VGPR cap + scratch-spill storm; observed behavior matches CUDA semantics
// (2nd arg = min WORKGROUPS per CU). (512,2) -> 16 waves/CU -> 128-VGPR cap,
// which fits the ~100-reg working set (w2a/w2b + acc[27]) with no spill,
// while LDS (~69KB) still allows 2 blocks/CU for barrier-drain overlap.

struct U2 { uint32_t x, y; };

// JAX Threefry-2x32 (20 rounds) — verified bit-exact in rounds 1-4
__device__ __forceinline__ U2 tf2x32(uint32_t k0, uint32_t k1, uint32_t x0, uint32_t x1) {
  uint32_t k2 = k0 ^ k1 ^ 0x1BD11BDAu;
#define TFROT(r) { x0 += x1; x1 = (x1 << (r)) | (x1 >> (32 - (r))); x1 ^= x0; }
  x0 += k0; x1 += k1;
  TFROT(13) TFROT(15) TFROT(26) TFROT(6)
  x0 += k1; x1 += k2 + 1u;
  TFROT(17) TFROT(29) TFROT(16) TFROT(24)
  x0 += k2; x1 += k0 + 2u;
  TFROT(13) TFROT(15) TFROT(26) TFROT(6)
  x0 += k0; x1 += k1 + 3u;
  TFROT(17) TFROT(29) TFROT(16) TFROT(24)
  x0 += k1; x1 += k2 + 4u;
  TFROT(13) TFROT(15) TFROT(26) TFROT(6)
  x0 += k2; x1 += k0 + 5u;
#undef TFROT
  return {x0, x1};
}

__device__ __forceinline__ float lrelu(float v) { return fmaxf(v, 0.1f * v); }

#define WOFF 4096   // init h1 window lives at s_stage[WOFF .. WOFF+2560)

// phase-B partial: 5x5 delta_h1(ic) (*) w2 -> 3 output rows (chunk CCH), acc[27]
template<int CCH>
__device__ __forceinline__ void pb_accum(const float (&w2)[25], const float* h1d_ic,
                                         float (&acc)[27]) {
  #pragma unroll
  for (int dyp = 0; dyp < 5; ++dyp) {
    if (dyp + 4 < 3 * CCH || dyp + 4 > 3 * CCH + 6) continue;   // compile-time fold
    float h[5];
    #pragma unroll
    for (int dxp = 0; dxp < 5; ++dxp) h[dxp] = h1d_ic[(dyp * 5 + dxp) * 32];
    #pragma unroll
    for (int u2 = 0; u2 < 3; ++u2) {
      const int ky = dyp + 4 - 3 * CCH - u2;
      if (ky < 0 || ky > 4) continue;                           // compile-time fold
      #pragma unroll
      for (int kx = 0; kx < 5; ++kx) {
        const float w = w2[ky * 5 + kx];
        #pragma unroll
        for (int dxp = 0; dxp < 5; ++dxp)
          acc[u2 * 9 + dxp - kx + 4] = fmaf(h[dxp], w, acc[u2 * 9 + dxp - kx + 4]);
      }
    }
  }
}

template<int CCH>
__device__ __forceinline__ void pb_chunk(const float (&w2a)[25], const float (&w2b)[25],
                                         int icp, const float* s_h1d, float* s_stage,
                                         float* s_a2, int tid, int lane, int wv,
                                         int i, int j) {
  float acc[27];
  #pragma unroll
  for (int q = 0; q < 27; ++q) acc[q] = 0.f;
  pb_accum<CCH>(w2a, s_h1d + icp, acc);
  pb_accum<CCH>(w2b, s_h1d + icp + 16, acc);
  #pragma unroll
  for (int q = 0; q < 27; ++q) acc[q] += __shfl_xor(acc[q], 32, 64);
  if (lane < 32) {
    #pragma unroll
    for (int q = 0; q < 27; ++q) s_stage[wv * 864 + q * 32 + lane] = acc[q];
  }
  __syncthreads();
  for (int e = tid; e < 864; e += 512) {
    float sm = 0.f;
    #pragma unroll
    for (int w = 0; w < 8; ++w) sm += s_stage[w * 864 + e];
    int q = e >> 5, o3 = e & 31;
    int u2 = q / 9, V = q - 9 * u2;
    int idx = (((i - 4 + 3 * CCH + u2) & 15) * 16 + ((j - 4 + V) & 15)) * 32 + o3;
    s_a2[idx] += sm;
  }
  __syncthreads();
}

// init conv2 partial for one a2 row, one ic: 16 columns
__device__ __forceinline__ void init_conv2_half(const float (&w2)[25], int icc,
                                                const float* s_stage, float (&acc)[16]) {
  #pragma unroll
  for (int ky = 0; ky < 5; ++ky) {
    float h[16];
    #pragma unroll
    for (int col = 0; col < 16; ++col) h[col] = s_stage[WOFF + ky * 512 + col * 32 + icc];
    #pragma unroll
    for (int kx = 0; kx < 5; ++kx) {
      const float w = w2[ky * 5 + kx];
      #pragma unroll
      for (int X = 0; X < 16; ++X)
        acc[X] = fmaf(h[(X + kx - 2) & 15], w, acc[X]);
    }
  }
}

__launch_bounds__(512, 2)
__global__ void van_kernel(const float* __restrict__ gx,
                           const float* __restrict__ gw1, const float* __restrict__ gb1,
                           const float* __restrict__ gw2, const float* __restrict__ gb2,
                           const float* __restrict__ gw3, const float* __restrict__ gb3,
                           float* __restrict__ out, int B) {
  __shared__ __align__(16) float s_xf[784];        // x with +/-6 circular halo (28x28)
  __shared__ __align__(16) float s_w1[800];
  __shared__ float s_b1[32], s_b2[32];
  __shared__ float s_u[64];
  __shared__ float s_c3[8];
  __shared__ __align__(16) float s_h1d[800];       // delta_h1: [pos25][ic32]
  __shared__ __align__(16) float s_a2[8192];       // a2 (+b2): [(row*16+col)*32+oc]
  __shared__ __align__(16) float s_stage[6912];    // 8x864 (main) / 8x512 + h1 window (init)

  const int tid  = threadIdx.x;
  const int bg   = blockIdx.x;
  const int lane = tid & 63;
  const int wv   = tid >> 6;
  const int oc   = tid & 31;   // conv2 out-channel
  const int icp  = tid >> 5;   // conv2 in-channel pair base: handles icp and icp+16

  // ---------------- setup ----------------
  const float b3v = gb3[0];
  float w2a[25], w2b[25];
  {
    const float* pa = gw2 + (oc * 32 + icp) * 25;         // w2[oc][icp][.]
    const float* pb = gw2 + (oc * 32 + icp + 16) * 25;    // w2[oc][icp+16][.]
    #pragma unroll
    for (int k = 0; k < 25; ++k) { w2a[k] = pa[k]; w2b[k] = pb[k]; }
  }
  float w3r1 = gw3[(tid & 31) * 25 + (tid >> 5)];         // entry e=tid: w3[oc][p]
  float w3r2 = 0.f;
  if (tid < 288) {
    int e = tid + 512;
    w3r2 = gw3[(e & 31) * 25 + (e >> 5)];
  }
  s_w1[tid] = gw1[tid];
  if (tid < 288) s_w1[tid + 512] = gw1[tid + 512];
  if (tid < 32)  { s_b1[tid] = gb1[tid]; s_b2[tid] = gb2[tid]; }
  {
    int rr = tid / 28, cc = tid - rr * 28;
    s_xf[tid] = gx[bg * 256 + ((rr - 6) & 15) * 16 + ((cc - 6) & 15)];
    if (tid < 272) {
      int t2 = tid + 512;
      int r2 = t2 / 28, c2 = t2 - r2 * 28;
      s_xf[t2] = gx[bg * 256 + ((r2 - 6) & 15) * 16 + ((c2 - 6) & 15)];
    }
  }
  if (tid < 64) {
    U2 key = tf2x32(0u, 42u, 0u, (uint32_t)tid);
    U2 tt  = tf2x32(key.x, key.y, 0u, (uint32_t)bg);
    uint32_t bits = tt.x ^ tt.y;
    s_u[tid] = __uint_as_float(0x3F800000u | (bits >> 9)) - 1.0f;
  }
  __syncthreads();

  // ---------------- init: a2 field row by row (h1 window recomputed) ----------------
  #pragma unroll 1
  for (int t = 0; t < 16; ++t) {
    // 5-row h1 window: slot r5 holds field row (t+r5-2)&15; thread = (col,ic)
    {
      const int colW = tid >> 5, icW = tid & 31;
      const float* wp = &s_w1[icW * 25];
      const float bb = s_b1[icW];
      #pragma unroll
      for (int r5 = 0; r5 < 5; ++r5) {
        int f = (t + r5 - 2) & 15;
        float a = bb;
        #pragma unroll
        for (int ky = 0; ky < 5; ++ky)
          #pragma unroll
          for (int kx = 0; kx < 5; ++kx)
            a = fmaf(s_xf[(f + 4 + ky) * 28 + colW + 4 + kx], wp[ky * 5 + kx], a);
        s_stage[WOFF + r5 * 512 + tid] = lrelu(a);
      }
    }
    __syncthreads();
    float acc[16];
    #pragma unroll
    for (int X = 0; X < 16; ++X) acc[X] = 0.f;
    init_conv2_half(w2a, icp, s_stage, acc);
    init_conv2_half(w2b, icp + 16, s_stage, acc);
    #pragma unroll
    for (int X = 0; X < 16; ++X) acc[X] += __shfl_xor(acc[X], 32, 64);
    if (lane < 32) {
      #pragma unroll
      for (int X = 0; X < 16; ++X) s_stage[wv * 512 + X * 32 + lane] = acc[X];
    }
    __syncthreads();
    {
      float sm = 0.f;
      #pragma unroll
      for (int w = 0; w < 8; ++w) sm += s_stage[w * 512 + tid];
      s_a2[t * 512 + tid] = sm + s_b2[tid & 31];
    }
    __syncthreads();
  }

  // ---------------- main autoregressive loop ----------------
  float logq = 0.f;
  #pragma unroll 1
  for (int s = 0; s < 64; ++s) {
    const int i = 2 * (s >> 3) + 1;
    const int j = 2 * (s & 7) + 1;

    // ---- conv3 from maintained a2 (800 terms over 512 threads) ----
    float v3;
    {
      int p1 = tid >> 5, o1 = tid & 31;
      int dy = p1 / 5, dx = p1 - 5 * dy;
      int idx = (((i + dy - 2) & 15) * 16 + ((j + dx - 2) & 15)) * 32 + o1;
      v3 = lrelu(s_a2[idx]) * w3r1;
      if (tid < 288) {
        int e = tid + 512, p2 = e >> 5, o2 = e & 31;
        int dy2 = p2 / 5, dx2 = p2 - 5 * dy2;
        int idx2 = (((i + dy2 - 2) & 15) * 16 + ((j + dx2 - 2) & 15)) * 32 + o2;
        v3 = fmaf(lrelu(s_a2[idx2]), w3r2, v3);
      }
    }
    #pragma unroll
    for (int m = 32; m >= 1; m >>= 1) v3 += __shfl_xor(v3, m, 64);
    if (lane == 0) s_c3[wv] = v3;
    __syncthreads();

    // ---- sample (all threads, redundant & identical) ----
    float logit = b3v;
    #pragma unroll
    for (int v = 0; v < 8; ++v) logit += s_c3[v];
    const float pr   = 1.f / (1.f + expf(-logit));
    const float u    = s_u[s];
    const float samp = (u < pr) ? 1.f : -1.f;
    const float xold = s_xf[(i + 6) * 28 + (j + 6)];
    logq += (samp > 0.f) ? logf(pr + 1e-7f) : logf(1.f - pr + 1e-7f);

    if (samp == xold) { __syncthreads(); continue; }   // block-uniform skip (~50%)

    // ---- phase A: delta_h1 at 25 positions x 32 ic (800 entries) ----
    {
      const float delta = samp - xold;                 // +/-2
      #pragma unroll
      for (int rep = 0; rep < 2; ++rep) {
        int e = tid + rep * 512;
        if (rep == 1 && tid >= 288) break;
        int p = e >> 5, icA = e & 31;
        int dyq = p / 5, dxq = p - 5 * dyq;
        const float* wp = &s_w1[icA * 25];
        float a1v = s_b1[icA];
        int base = (i + dyq + 2) * 28 + (j + dxq + 2);
        #pragma unroll
        for (int ky = 0; ky < 5; ++ky)
          #pragma unroll
          for (int kx = 0; kx < 5; ++kx)
            a1v = fmaf(s_xf[base + ky * 28 + kx], wp[ky * 5 + kx], a1v);
        float a1n = fmaf(delta, wp[(4 - dyq) * 5 + (4 - dxq)], a1v);
        s_h1d[p * 32 + icA] = lrelu(a1n) - lrelu(a1v);
      }
    }
    __syncthreads();

    if (tid == 511) {                                  // update x halo copies
      int r1 = i + 6, c1 = j + 6;
      int r2 = (i < 6) ? i + 22 : ((i >= 10) ? i - 10 : r1);
      int c2 = (j < 6) ? j + 22 : ((j >= 10) ? j - 10 : c1);
      s_xf[r1 * 28 + c1] = samp; s_xf[r1 * 28 + c2] = samp;
      s_xf[r2 * 28 + c1] = samp; s_xf[r2 * 28 + c2] = samp;
    }

    // ---- phase B: 5x5 delta_h1 (*) w2 -> 9x9 a2 update, 3 chunks x 3 rows ----
    pb_chunk<0>(w2a, w2b, icp, s_h1d, s_stage, s_a2, tid, lane, wv, i, j);
    pb_chunk<1>(w2a, w2b, icp, s_h1d, s_stage, s_a2, tid, lane, wv, i, j);
    pb_chunk<2>(w2a, w2b, icp, s_h1d, s_stage, s_a2, tid, lane, wv, i, j);
  }

  // ---------------- output ----------------
  if (tid < 256)
    out[bg * 256 + tid] = s_xf[((tid >> 4) + 6) * 28 + (tid & 15) + 6];
  if (tid == 0)
    out[B * 256 + bg] = logq;
}

extern "C" void kernel_launch(void* const* d_in, const int* in_sizes, int n_in,
                              void* d_out, int out_size, void* d_ws, size_t ws_size,
                              hipStream_t stream) {
  const float* gx  = (const float*)d_in[0];
  const float* gw1 = (const float*)d_in[1];
  const float* gb1 = (const float*)d_in[2];
  const float* gw2 = (const float*)d_in[3];
  const float* gb2 = (const float*)d_in[4];
  const float* gw3 = (const float*)d_in[5];
  const float* gb3 = (const float*)d_in[6];
  float* out = (float*)d_out;
  const int B = in_sizes[0] / 256;

  hipLaunchKernelGGL(van_kernel, dim3(B), dim3(512), 0, stream,
                     gx, gw1, gb1, gw2, gb2, gw3, gb3, out, B);
}